// Round 4
// baseline (146.035 us; speedup 1.0000x reference)
//
#include <hip/hip_runtime.h>

#define N   2048
#define NT  256
#define EPK 32  // one wave (64 lanes) holds a full row: 64*32 = 2048

typedef unsigned int u32;

// monotone float->uint key: ascending uint order == ascending float order
__device__ __forceinline__ u32 fkey(float f) {
  u32 u = __float_as_uint(f);
  return (u & 0x80000000u) ? ~u : (u | 0x80000000u);
}

__device__ __forceinline__ u32 umin32(u32 a, u32 b) { return a < b ? a : b; }
__device__ __forceinline__ u32 umax32(u32 a, u32 b) { return a < b ? b : a; }

// lane-xor exchange of a u32, cheapest available unit per distance:
//   xor1/xor2: DPP quad_perm (VALU)      xor8: DPP row_ror:8 (rot by 8 in 16 == xor8)
//   xor4/xor16: ds_swizzle BitMode       xor32: v_permlane32_swap (gfx950 VALU)
template <int D>
__device__ __forceinline__ u32 exch(u32 x, int lane) {
  if constexpr (D == 1) {
    return (u32)__builtin_amdgcn_update_dpp((int)x, (int)x, 0xB1, 0xF, 0xF, true);
  } else if constexpr (D == 2) {
    return (u32)__builtin_amdgcn_update_dpp((int)x, (int)x, 0x4E, 0xF, 0xF, true);
  } else if constexpr (D == 4) {
    return (u32)__builtin_amdgcn_ds_swizzle((int)x, 0x101F);  // (lane&31)^4
  } else if constexpr (D == 8) {
    return (u32)__builtin_amdgcn_update_dpp((int)x, (int)x, 0x128, 0xF, 0xF, true);
  } else if constexpr (D == 16) {
    return (u32)__builtin_amdgcn_ds_swizzle((int)x, 0x401F);  // (lane&31)^16
  } else {  // D == 32
    int a = (int)x, b = (int)x;
    asm("v_permlane32_swap_b32 %0, %1" : "+v"(a), "+v"(b));
    // a' lanes[32:63] = x lanes[0:31]; b' lanes[0:31] = x lanes[32:63]
    return (lane & 32) ? (u32)a : (u32)b;
  }
}

// one bitonic pass at lane-distance D (element distance 32*D), all 32 elems
template <int D>
__device__ __forceinline__ void sh_pass(u32* kv, bool keep_min, int lane) {
#pragma unroll
  for (int m = 0; m < EPK; ++m) {
    u32 o = exch<D>(kv[m], lane);
    u32 mn = umin32(kv[m], o), mx = umax32(kv[m], o);
    kv[m] = keep_min ? mn : mx;
  }
}

// in-lane pass at element distance J (<=16); UPEXPR may use m (compile-time
// foldable after unroll) and captured runtime bools
#define INPASS(J, UPEXPR)                               \
  {                                                     \
    _Pragma("unroll")                                   \
    for (int m = 0; m < EPK; ++m)                       \
      if ((m & (J)) == 0) {                             \
        const bool up_ = (UPEXPR);                      \
        u32 x = kv[m], y = kv[m | (J)];                 \
        u32 mn = umin32(x, y), mx = umax32(x, y);       \
        kv[m] = up_ ? mn : mx;                          \
        kv[m | (J)] = up_ ? mx : mn;                    \
      }                                                 \
  }

__global__ __launch_bounds__(NT, 4) void listmle_kernel(
    const float* __restrict__ input1,
    const float* __restrict__ input2,
    const int* __restrict__ mask2,
    float* __restrict__ out) {
  __shared__ float rows[4][N];  // 32 KB: one 8 KB row slab per wave

  const int tid = threadIdx.x;
  const int lane = tid & 63;
  const int wv = tid >> 6;
  const int p = blockIdx.x * 4 + wv;  // p = b*32 + h
  const int lane32 = lane * EPK;      // this lane's 32 consecutive elements

  // ---- load 32 elems (128B/lane), build u32 sort items ----
  // key = fkey(v) top-21 bits | 11-bit idx (tiebreak == stable argsort);
  // masked -> 0xFFFFF800|idx: above any unmasked N(0,1) fkey, sorts to end
  // in ascending-idx order exactly like the reference's tied MASK_FILL.
  const size_t base2 = (size_t)p * N + (size_t)lane32;
  const float4* i2v = (const float4*)(input2 + base2);
  const int4* m2v = (const int4*)(mask2 + base2);
  u32 kv[EPK];
#pragma unroll
  for (int q = 0; q < 8; ++q) {
    float4 vv = i2v[q];
    int4 mm = m2v[q];
    const u32 gi = (u32)(lane32 + 4 * q);
    float vs[4] = {vv.x, vv.y, vv.z, vv.w};
    int ms[4] = {mm.x, mm.y, mm.z, mm.w};
#pragma unroll
    for (int r = 0; r < 4; ++r) {
      kv[4 * q + r] = (ms[r] > 0) ? ((fkey(vs[r]) & 0xFFFFF800u) | (gi + r))
                                  : (0xFFFFF800u | (gi + r));
    }
  }

  // ---- bitonic sort, fully wave-synchronous (0 barriers) ----
  // stages k=2..16: directions compile-time in m
  INPASS(1, (m & 2) == 0)
  INPASS(2, (m & 4) == 0) INPASS(1, (m & 4) == 0)
  INPASS(4, (m & 8) == 0) INPASS(2, (m & 8) == 0) INPASS(1, (m & 8) == 0)
  INPASS(8, (m & 16) == 0) INPASS(4, (m & 16) == 0)
  INPASS(2, (m & 16) == 0) INPASS(1, (m & 16) == 0)
  {  // k=32: dir = lane parity
    const bool up = (lane & 1) == 0;
    INPASS(16, up) INPASS(8, up) INPASS(4, up) INPASS(2, up) INPASS(1, up)
  }
  {  // k=64
    const bool up = (lane & 2) == 0;
    sh_pass<1>(kv, ((lane & 1) == 0) == up, lane);
    INPASS(16, up) INPASS(8, up) INPASS(4, up) INPASS(2, up) INPASS(1, up)
  }
  {  // k=128
    const bool up = (lane & 4) == 0;
    sh_pass<2>(kv, ((lane & 2) == 0) == up, lane);
    sh_pass<1>(kv, ((lane & 1) == 0) == up, lane);
    INPASS(16, up) INPASS(8, up) INPASS(4, up) INPASS(2, up) INPASS(1, up)
  }
  {  // k=256
    const bool up = (lane & 8) == 0;
    sh_pass<4>(kv, ((lane & 4) == 0) == up, lane);
    sh_pass<2>(kv, ((lane & 2) == 0) == up, lane);
    sh_pass<1>(kv, ((lane & 1) == 0) == up, lane);
    INPASS(16, up) INPASS(8, up) INPASS(4, up) INPASS(2, up) INPASS(1, up)
  }
  {  // k=512
    const bool up = (lane & 16) == 0;
    sh_pass<8>(kv, ((lane & 8) == 0) == up, lane);
    sh_pass<4>(kv, ((lane & 4) == 0) == up, lane);
    sh_pass<2>(kv, ((lane & 2) == 0) == up, lane);
    sh_pass<1>(kv, ((lane & 1) == 0) == up, lane);
    INPASS(16, up) INPASS(8, up) INPASS(4, up) INPASS(2, up) INPASS(1, up)
  }
  {  // k=1024
    const bool up = (lane & 32) == 0;
    sh_pass<16>(kv, ((lane & 16) == 0) == up, lane);
    sh_pass<8>(kv, ((lane & 8) == 0) == up, lane);
    sh_pass<4>(kv, ((lane & 4) == 0) == up, lane);
    sh_pass<2>(kv, ((lane & 2) == 0) == up, lane);
    sh_pass<1>(kv, ((lane & 1) == 0) == up, lane);
    INPASS(16, up) INPASS(8, up) INPASS(4, up) INPASS(2, up) INPASS(1, up)
  }
  {  // k=2048: final ascending merge, up == true (compile-time tails)
    sh_pass<32>(kv, (lane & 32) == 0, lane);
    sh_pass<16>(kv, (lane & 16) == 0, lane);
    sh_pass<8>(kv, (lane & 8) == 0, lane);
    sh_pass<4>(kv, (lane & 4) == 0, lane);
    sh_pass<2>(kv, (lane & 2) == 0, lane);
    sh_pass<1>(kv, (lane & 1) == 0, lane);
    INPASS(16, true) INPASS(8, true) INPASS(4, true) INPASS(2, true)
    INPASS(1, true)
  }

  // ---- pack sorted (idx, keep) to 16 regs: idx in [0,11), keep at bit 11 ----
  u32 pk[EPK / 2];
#pragma unroll
  for (int t = 0; t < EPK / 2; ++t) {
    u32 a = kv[2 * t], b = kv[2 * t + 1];
    u32 ia = (a & 0x7FFu) | ((a < 0xFFFFF800u) ? 0x800u : 0u);
    u32 ib = (b & 0x7FFu) | ((b < 0xFFFFF800u) ? 0x800u : 0u);
    pk[t] = ia | (ib << 16);
  }

  // ---- channel phase: per-wave private LDS slab, no barriers ----
  const int b = p >> 5, h = p & 31;
  float* rowbuf = rows[wv];
  for (int c = 0; c < 4; ++c) {
    const float* r1 = input1 + ((size_t)((b * 4 + c) * 32 + h)) * N;
#pragma unroll
    for (int q = 0; q < 8; ++q)
      ((float4*)rowbuf)[lane + 64 * q] = ((const float4*)r1)[lane + 64 * q];
    // same-wave LDS RAW/WAR: compiler-inserted lgkmcnt, no barrier needed

    float e[EPK];
    float lsum = 0.f;
#pragma unroll
    for (int m = 0; m < EPK; ++m) {
      u32 info = (pk[m >> 1] >> ((m & 1) * 16)) & 0xFFFFu;
      float v = rowbuf[info & 0x7FFu];  // gather by sorted original index
      float pe = (info & 0x800u) ? __expf(v) : 0.f;
      e[m] = pe;
      lsum += pe;
    }

    // wave-exclusive scan of per-lane sums (lane order == sorted-block order)
    float inc = lsum;
#pragma unroll
    for (int d = 1; d < 64; d <<= 1) {
      float o = __shfl_up(inc, d, 64);
      if (lane >= d) inc += o;
    }
    float cum = inc - lsum;  // exclusive prefix for this lane

    float prod = 1.f;
#pragma unroll
    for (int m = 0; m < EPK; ++m) {
      cum += e[m];
      u32 info = pk[m >> 1] >> ((m & 1) * 16);
      if (info & 0x800u) prod *= __fdividef(e[m] + 1e-9f, cum + 1e-9f);
    }
#pragma unroll
    for (int d = 1; d < 64; d <<= 1) prod *= __shfl_xor(prod, d, 64);
    if (lane == 0) out[(size_t)p * 4 + c] = prod;
  }
}

extern "C" void kernel_launch(void* const* d_in, const int* in_sizes, int n_in,
                              void* d_out, int out_size, void* d_ws, size_t ws_size,
                              hipStream_t stream) {
  const float* input1 = (const float*)d_in[0];
  // d_in[1] = mask1 — unused by the reference forward
  const float* input2 = (const float*)d_in[2];
  const int* mask2 = (const int*)d_in[3];
  float* out = (float*)d_out;

  const int problems = 128 * 32;  // bs * nh; 4 problems (waves) per block
  listmle_kernel<<<problems / 4, NT, 0, stream>>>(input1, input2, mask2, out);
}

// Round 5
// 72.678 us; speedup vs baseline: 2.0093x; 2.0093x over previous
//
#include <hip/hip_runtime.h>

#define N   2048
#define NT  256
#define EPK 32  // one wave (64 lanes) holds a full row: 64*32 = 2048

typedef unsigned int u32;

// monotone float->uint key: ascending uint order == ascending float order
__device__ __forceinline__ u32 fkey(float f) {
  u32 u = __float_as_uint(f);
  return (u & 0x80000000u) ? ~u : (u | 0x80000000u);
}

__device__ __forceinline__ u32 umin32(u32 a, u32 b) { return a < b ? a : b; }
__device__ __forceinline__ u32 umax32(u32 a, u32 b) { return a < b ? b : a; }

// lane-xor exchange of a u32, cheapest available unit per distance:
//   xor1/xor2: DPP quad_perm (VALU)      xor8: DPP row_ror:8 (rot by 8 in 16 == xor8)
//   xor4/xor16: ds_swizzle BitMode       xor32: v_permlane32_swap (gfx950 VALU)
template <int D>
__device__ __forceinline__ u32 exch(u32 x, int lane) {
  if constexpr (D == 1) {
    return (u32)__builtin_amdgcn_update_dpp((int)x, (int)x, 0xB1, 0xF, 0xF, true);
  } else if constexpr (D == 2) {
    return (u32)__builtin_amdgcn_update_dpp((int)x, (int)x, 0x4E, 0xF, 0xF, true);
  } else if constexpr (D == 4) {
    return (u32)__builtin_amdgcn_ds_swizzle((int)x, 0x101F);  // (lane&31)^4
  } else if constexpr (D == 8) {
    return (u32)__builtin_amdgcn_update_dpp((int)x, (int)x, 0x128, 0xF, 0xF, true);
  } else if constexpr (D == 16) {
    return (u32)__builtin_amdgcn_ds_swizzle((int)x, 0x401F);  // (lane&31)^16
  } else {  // D == 32
    int a = (int)x, b = (int)x;
    asm("v_permlane32_swap_b32 %0, %1" : "+v"(a), "+v"(b));
    // a' lanes[32:63] = x lanes[0:31]; b' lanes[0:31] = x lanes[32:63]
    return (lane & 32) ? (u32)a : (u32)b;
  }
}

// one bitonic pass at lane-distance D (element distance 32*D), all 32 elems
template <int D>
__device__ __forceinline__ void sh_pass(u32* kv, bool keep_min, int lane) {
#pragma unroll
  for (int m = 0; m < EPK; ++m) {
    u32 o = exch<D>(kv[m], lane);
    u32 mn = umin32(kv[m], o), mx = umax32(kv[m], o);
    kv[m] = keep_min ? mn : mx;
  }
}

// in-lane pass at element distance J (<=16); UPEXPR may use m (compile-time
// foldable after unroll) and captured runtime bools
#define INPASS(J, UPEXPR)                               \
  {                                                     \
    _Pragma("unroll")                                   \
    for (int m = 0; m < EPK; ++m)                       \
      if ((m & (J)) == 0) {                             \
        const bool up_ = (UPEXPR);                      \
        u32 x = kv[m], y = kv[m | (J)];                 \
        u32 mn = umin32(x, y), mx = umax32(x, y);       \
        kv[m] = up_ ? mn : mx;                          \
        kv[m | (J)] = up_ ? mx : mn;                    \
      }                                                 \
  }

__global__ __launch_bounds__(NT, 4) void listmle_kernel(
    const float* __restrict__ input1,
    const float* __restrict__ input2,
    const int* __restrict__ mask2,
    float* __restrict__ out) {
  __shared__ __align__(16) float rows[4][N];  // 32 KB: 8 KB slab per wave

  const int tid = threadIdx.x;
  const int lane = tid & 63;
  const int wv = tid >> 6;
  const int p = blockIdx.x * 4 + wv;  // p = b*32 + h
  const int lane32 = lane * EPK;      // this lane's 32 consecutive elements

  // ---- coalesced load (16B/lane x 64 = 1KB/instr, every line used once),
  //      build u32 keys in regs, XOR-swizzled LDS transpose ----
  // key = fkey(v) top-21 bits | 11-bit idx (tiebreak == stable argsort);
  // masked -> 0xFFFFF800|idx: above any finite fkey, sorts to end in
  // ascending-idx order exactly like the reference's tied MASK_FILL.
  u32* keys = (u32*)rows[wv];  // slab reused later for the channel rows
  {
    const float4* i2v = (const float4*)(input2 + (size_t)p * N);
    const int4* m2v = (const int4*)(mask2 + (size_t)p * N);
#pragma unroll
    for (int q = 0; q < 8; ++q) {
      float4 vv = i2v[lane + 64 * q];
      int4 mm = m2v[lane + 64 * q];
      const u32 i0 = (u32)(4 * (lane + 64 * q));
      float vs[4] = {vv.x, vv.y, vv.z, vv.w};
      int ms[4] = {mm.x, mm.y, mm.z, mm.w};
#pragma unroll
      for (int r = 0; r < 4; ++r) {
        u32 idx = i0 + r;
        u32 key = (ms[r] > 0) ? ((fkey(vs[r]) & 0xFFFFF800u) | idx)
                              : (0xFFFFF800u | idx);
        // slot swizzle: bank = (idx ^ (idx>>5)) % 32 -> worst 2-way (free)
        keys[idx ^ ((idx >> 5) & 31u)] = key;
      }
    }
  }
  // read back blocked: lane gets elements [lane*32, lane*32+32)
  // (same-wave LDS RAW: compiler-inserted lgkmcnt, wave-synchronous, no barrier)
  u32 kv[EPK];
#pragma unroll
  for (int m = 0; m < EPK; ++m) {
    u32 idx = (u32)(lane32 + m);
    kv[m] = keys[idx ^ ((u32)lane & 31u)];  // (idx>>5)&31 == lane&31 here
  }

  // ---- bitonic sort, fully wave-synchronous (0 barriers) ----
  INPASS(1, (m & 2) == 0)
  INPASS(2, (m & 4) == 0) INPASS(1, (m & 4) == 0)
  INPASS(4, (m & 8) == 0) INPASS(2, (m & 8) == 0) INPASS(1, (m & 8) == 0)
  INPASS(8, (m & 16) == 0) INPASS(4, (m & 16) == 0)
  INPASS(2, (m & 16) == 0) INPASS(1, (m & 16) == 0)
  {  // k=32: dir = lane parity
    const bool up = (lane & 1) == 0;
    INPASS(16, up) INPASS(8, up) INPASS(4, up) INPASS(2, up) INPASS(1, up)
  }
  {  // k=64
    const bool up = (lane & 2) == 0;
    sh_pass<1>(kv, ((lane & 1) == 0) == up, lane);
    INPASS(16, up) INPASS(8, up) INPASS(4, up) INPASS(2, up) INPASS(1, up)
  }
  {  // k=128
    const bool up = (lane & 4) == 0;
    sh_pass<2>(kv, ((lane & 2) == 0) == up, lane);
    sh_pass<1>(kv, ((lane & 1) == 0) == up, lane);
    INPASS(16, up) INPASS(8, up) INPASS(4, up) INPASS(2, up) INPASS(1, up)
  }
  {  // k=256
    const bool up = (lane & 8) == 0;
    sh_pass<4>(kv, ((lane & 4) == 0) == up, lane);
    sh_pass<2>(kv, ((lane & 2) == 0) == up, lane);
    sh_pass<1>(kv, ((lane & 1) == 0) == up, lane);
    INPASS(16, up) INPASS(8, up) INPASS(4, up) INPASS(2, up) INPASS(1, up)
  }
  {  // k=512
    const bool up = (lane & 16) == 0;
    sh_pass<8>(kv, ((lane & 8) == 0) == up, lane);
    sh_pass<4>(kv, ((lane & 4) == 0) == up, lane);
    sh_pass<2>(kv, ((lane & 2) == 0) == up, lane);
    sh_pass<1>(kv, ((lane & 1) == 0) == up, lane);
    INPASS(16, up) INPASS(8, up) INPASS(4, up) INPASS(2, up) INPASS(1, up)
  }
  {  // k=1024
    const bool up = (lane & 32) == 0;
    sh_pass<16>(kv, ((lane & 16) == 0) == up, lane);
    sh_pass<8>(kv, ((lane & 8) == 0) == up, lane);
    sh_pass<4>(kv, ((lane & 4) == 0) == up, lane);
    sh_pass<2>(kv, ((lane & 2) == 0) == up, lane);
    sh_pass<1>(kv, ((lane & 1) == 0) == up, lane);
    INPASS(16, up) INPASS(8, up) INPASS(4, up) INPASS(2, up) INPASS(1, up)
  }
  {  // k=2048: final ascending merge (up == true, compile-time tails)
    sh_pass<32>(kv, (lane & 32) == 0, lane);
    sh_pass<16>(kv, (lane & 16) == 0, lane);
    sh_pass<8>(kv, (lane & 8) == 0, lane);
    sh_pass<4>(kv, (lane & 4) == 0, lane);
    sh_pass<2>(kv, (lane & 2) == 0, lane);
    sh_pass<1>(kv, (lane & 1) == 0, lane);
    INPASS(16, true) INPASS(8, true) INPASS(4, true) INPASS(2, true)
    INPASS(1, true)
  }

  // ---- pack sorted (idx, keep) to 16 regs: idx bits [0,11), keep at bit 11 ----
  u32 pk[EPK / 2];
#pragma unroll
  for (int t = 0; t < EPK / 2; ++t) {
    u32 a = kv[2 * t], b = kv[2 * t + 1];
    u32 ia = (a & 0x7FFu) | ((a < 0xFFFFF800u) ? 0x800u : 0u);
    u32 ib = (b & 0x7FFu) | ((b < 0xFFFFF800u) ? 0x800u : 0u);
    pk[t] = ia | (ib << 16);
  }

  // ---- channel phase: per-wave private LDS slab, no barriers ----
  const int b = p >> 5, h = p & 31;
  float* rowbuf = rows[wv];
  for (int c = 0; c < 4; ++c) {
    const float* r1 = input1 + ((size_t)((b * 4 + c) * 32 + h)) * N;
#pragma unroll
    for (int q = 0; q < 8; ++q)
      ((float4*)rowbuf)[lane + 64 * q] = ((const float4*)r1)[lane + 64 * q];
    // same-wave LDS RAW/WAR: compiler-inserted lgkmcnt, no barrier needed

    float e[EPK];
    float lsum = 0.f;
#pragma unroll
    for (int m = 0; m < EPK; ++m) {
      u32 info = (pk[m >> 1] >> ((m & 1) * 16)) & 0xFFFFu;
      float v = rowbuf[info & 0x7FFu];  // gather by sorted original index
      float pe = (info & 0x800u) ? __expf(v) : 0.f;
      e[m] = pe;
      lsum += pe;
    }

    // wave-exclusive scan of per-lane sums (lane order == sorted-block order)
    float inc = lsum;
#pragma unroll
    for (int d = 1; d < 64; d <<= 1) {
      float o = __shfl_up(inc, d, 64);
      if (lane >= d) inc += o;
    }
    float cum = inc - lsum;  // exclusive prefix for this lane

    float prod = 1.f;
#pragma unroll
    for (int m = 0; m < EPK; ++m) {
      cum += e[m];
      u32 info = pk[m >> 1] >> ((m & 1) * 16);
      if (info & 0x800u) prod *= __fdividef(e[m] + 1e-9f, cum + 1e-9f);
    }
#pragma unroll
    for (int d = 1; d < 64; d <<= 1) prod *= __shfl_xor(prod, d, 64);
    if (lane == 0) out[(size_t)p * 4 + c] = prod;
  }
}

extern "C" void kernel_launch(void* const* d_in, const int* in_sizes, int n_in,
                              void* d_out, int out_size, void* d_ws, size_t ws_size,
                              hipStream_t stream) {
  const float* input1 = (const float*)d_in[0];
  // d_in[1] = mask1 — unused by the reference forward
  const float* input2 = (const float*)d_in[2];
  const int* mask2 = (const int*)d_in[3];
  float* out = (float*)d_out;

  const int problems = 128 * 32;  // bs * nh; 4 problems (waves) per block
  listmle_kernel<<<problems / 4, NT, 0, stream>>>(input1, input2, mask2, out);
}